// Round 9
// baseline (398.253 us; speedup 1.0000x reference)
//
#include <hip/hip_runtime.h>
#include <hip/hip_cooperative_groups.h>
#include <math.h>

namespace cg = cooperative_groups;

#define GG   64
#define TOT  2097152
#define THR  256
#define PPT  8
#define PTS  2048          // fused: points per block
#define NBLK 1024          // fused grid: needs 4 blocks/CU co-resident

// fused ws layout (floats):  ZP[0,512) ZT[512,1024) CNT[1024,1536) PART[1536,7680)
#define ZP_F   0
#define ZT_F   512
#define CNT_F  1024
#define PART_F 1536
// fallback (round-7) extra layout: PAIR[1536,2560) NV=2560 PART2[2816,2816+6*2048)
#define FB_PAIR 1536
#define FB_NV   2560
#define FB_PART 2816
#define FB_NBLK 2048
#define FB_PTS  1024
#define WS_ZERO_BYTES (7680 * 4)

#define LN2   0.6931471805599453f
#define LOG2E 1.4426950408889634f

__device__ __forceinline__ float fexp2(float x) { return __builtin_amdgcn_exp2f(x); }
__device__ __forceinline__ float flog2(float x) { return __builtin_amdgcn_logf(x); }
__device__ __forceinline__ float flog1p(float x) { return flog2(1.0f + x) * LN2; }

__device__ __forceinline__ float wredf(float v) {
#pragma unroll
    for (int o = 32; o > 0; o >>= 1) v += __shfl_down(v, o, 64);
    return v;
}

__device__ __forceinline__ unsigned pack_bf16(float a, float b) {
    unsigned ua = __float_as_uint(a), ub = __float_as_uint(b);
    ua = (ua + 0x7FFFu + ((ua >> 16) & 1u)) >> 16;
    ub = (ub + 0x7FFFu + ((ub >> 16) & 1u)) >> 16;
    return ua | (ub << 16);
}
__device__ __forceinline__ float unpk(unsigned u, int hi) {
    return __uint_as_float(hi ? (u & 0xFFFF0000u) : (u << 16));
}

// =================== FUSED cooperative kernel ===================
__global__ __launch_bounds__(THR, 4) void k_fused(
    const float* __restrict__ pp, const float* __restrict__ tp,
    const float* __restrict__ p2, const float* __restrict__ t2,
    const float* __restrict__ pv, const float* __restrict__ tv,
    const float* __restrict__ pd, const float* __restrict__ td,
    const float* __restrict__ pn, const float* __restrict__ tn,
    const float* __restrict__ cf, const int* __restrict__ mask,
    const int* __restrict__ grp, float* __restrict__ ws,
    float* __restrict__ out)
{
    cg::grid_group grid = cg::this_grid();
    __shared__ float sP[GG], sT[GG], sC[GG];
    __shared__ float sPairs[2 * GG];
    __shared__ float sred[4][6];
    __shared__ float s4[4];
    __shared__ float sNv;

    const int tid = threadIdx.x;
    const int base = (int)blockIdx.x * PTS;     // 2048 | NN: one batch per block
    const int b = base >> 18;
    const int p0 = base + PPT * tid;

    if (tid < GG) { sP[tid] = 0.f; sT[tid] = 0.f; sC[tid] = 0.f; }
    __syncthreads();

    // ---- Phase A: load pp/tp once, keep as packed bf16; group z-sums (f32)
    unsigned mb, gA, gB;
    {
        int4 m0 = *(const int4*)(mask + p0), m1 = *(const int4*)(mask + p0 + 4);
        int4 g0 = *(const int4*)(grp + p0),  g1 = *(const int4*)(grp + p0 + 4);
        mb = (m0.x & 1) | ((m0.y & 1) << 1) | ((m0.z & 1) << 2) | ((m0.w & 1) << 3)
           | ((m1.x & 1) << 4) | ((m1.y & 1) << 5) | ((m1.z & 1) << 6) | ((m1.w & 1) << 7);
        gA = (unsigned)g0.x | ((unsigned)g0.y << 8) | ((unsigned)g0.z << 16) | ((unsigned)g0.w << 24);
        gB = (unsigned)g1.x | ((unsigned)g1.y << 8) | ((unsigned)g1.z << 16) | ((unsigned)g1.w << 24);
    }
    unsigned ph[12], th[12];
    {
        const float4* ga = (const float4*)(pp + (size_t)p0 * 3);
        const float4* gb = (const float4*)(tp + (size_t)p0 * 3);
        float P[24], T[24];
#pragma unroll
        for (int j = 0; j < 6; j++) { *(float4*)&P[4 * j] = ga[j]; *(float4*)&T[4 * j] = gb[j]; }
#pragma unroll
        for (int k = 0; k < PPT; k++) {
            if ((mb >> k) & 1) {
                int g = (int)(((k < 4 ? gA : gB) >> (8 * (k & 3))) & 63u);
                atomicAdd(&sP[g], P[3 * k + 2]);
                atomicAdd(&sT[g], T[3 * k + 2]);
                atomicAdd(&sC[g], 1.f);
            }
        }
#pragma unroll
        for (int j = 0; j < 12; j++) {
            ph[j] = pack_bf16(P[2 * j], P[2 * j + 1]);
            th[j] = pack_bf16(T[2 * j], T[2 * j + 1]);
        }
    }
    __syncthreads();
    if (tid < GG) {
        float c = sC[tid];
        if (c != 0.f) {
            int e = b * GG + tid;
            atomicAdd(&ws[ZP_F + e], sP[tid]);
            atomicAdd(&ws[ZT_F + e], sT[tid]);
            atomicAdd(&ws[CNT_F + e], c);
        }
    }
    grid.sync();
    __threadfence();

    // ---- Phase A2: batch's 64 inverse-safe-mean pairs into LDS; block0: nvalid
    if (tid < GG) {
        int e = b * GG + tid;
        float c = ws[CNT_F + e];
        float mP = (c > 0.f) ? ws[ZP_F + e] / fmaxf(c, 1.f) : 1.f;
        float mT = (c > 0.f) ? ws[ZT_F + e] / fmaxf(c, 1.f) : 1.f;
        sPairs[2 * tid]     = 1.f / fmaxf(fabsf(mP), 1e-6f);
        sPairs[2 * tid + 1] = 1.f / fmaxf(fabsf(mT), 1e-6f);
    }
    if (blockIdx.x == 0) {
        float c = ws[CNT_F + tid] + ws[CNT_F + tid + 256];
        c = wredf(c);
        if ((tid & 63) == 0) s4[tid >> 6] = c;
        __syncthreads();
        if (tid == 0) sNv = s4[0] + s4[1] + s4[2] + s4[3];
    }
    __syncthreads();

    // ---- Phase B: loss terms
    float s3d = 0.f, s2 = 0.f, sv = 0.f, sd = 0.f, sn = 0.f, sc = 0.f;

    // L_3D from held bf16 registers
#pragma unroll
    for (int k = 0; k < PPT; k++) {
        float wk = (float)((mb >> k) & 1);
        int g = (int)(((k < 4 ? gA : gB) >> (8 * (k & 3))) & 63u);
        float ip = sPairs[2 * g], it = sPairs[2 * g + 1];
        float acc = 0.f;
#pragma unroll
        for (int c = 0; c < 3; c++) {
            int e = 3 * k + c;
            float a  = unpk(ph[e >> 1], e & 1) * ip;
            float bb = unpk(th[e >> 1], e & 1) * it;
            acc += fabsf(copysignf(flog1p(fabsf(a)), a) - copysignf(flog1p(fabsf(bb)), bb));
        }
        s3d += wk * acc;
    }
    // L_2D
    {
        const float4* ga = (const float4*)(p2 + (size_t)p0 * 2);
        const float4* gb = (const float4*)(t2 + (size_t)p0 * 2);
#pragma unroll
        for (int j = 0; j < 4; j++) {
            float4 A = ga[j], Bv = gb[j];
            float w0 = (float)((mb >> (2 * j)) & 1);
            float w1 = (float)((mb >> (2 * j + 1)) & 1);
            s2 += w0 * (fabsf(A.x - Bv.x) + fabsf(A.y - Bv.y))
                + w1 * (fabsf(A.z - Bv.z) + fabsf(A.w - Bv.w));
        }
    }
    // L_vis + L_conf
    {
        const float4* gx = (const float4*)(pv + p0);
        const float4* gt = (const float4*)(tv + p0);
        const float4* gc = (const float4*)(cf + p0);
#pragma unroll
        for (int j = 0; j < 2; j++) {
            float4 X = gx[j], Tg = gt[j], C = gc[j];
            const float xs[4] = {X.x, X.y, X.z, X.w};
            const float ts[4] = {Tg.x, Tg.y, Tg.z, Tg.w};
            const float cs[4] = {C.x, C.y, C.z, C.w};
#pragma unroll
            for (int k = 0; k < 4; k++) {
                float wk = (float)((mb >> (4 * j + k)) & 1);
                float x = xs[k];
                float soft = flog2(1.0f + fexp2(-fabsf(x) * LOG2E)) * LN2;
                sv += wk * (fmaxf(x, 0.f) - x * ts[k] + soft);
                sc += wk * cs[k];
            }
        }
    }
    // L_disp
    {
        const float4* ga = (const float4*)(pd + (size_t)p0 * 3);
        const float4* gb = (const float4*)(td + (size_t)p0 * 3);
        float P[24], T[24];
#pragma unroll
        for (int j = 0; j < 6; j++) { *(float4*)&P[4 * j] = ga[j]; *(float4*)&T[4 * j] = gb[j]; }
#pragma unroll
        for (int k = 0; k < PPT; k++) {
            float wk = (float)((mb >> k) & 1);
            sd += wk * (fabsf(P[3 * k] - T[3 * k]) + fabsf(P[3 * k + 1] - T[3 * k + 1])
                      + fabsf(P[3 * k + 2] - T[3 * k + 2]));
        }
    }
    // L_normal
    {
        const float4* ga = (const float4*)(pn + (size_t)p0 * 3);
        const float4* gb = (const float4*)(tn + (size_t)p0 * 3);
        float P[24], T[24];
#pragma unroll
        for (int j = 0; j < 6; j++) { *(float4*)&P[4 * j] = ga[j]; *(float4*)&T[4 * j] = gb[j]; }
#pragma unroll
        for (int k = 0; k < PPT; k++) {
            float wk = (float)((mb >> k) & 1);
            float ax = P[3 * k], ay = P[3 * k + 1], az = P[3 * k + 2];
            float bx = T[3 * k], by = T[3 * k + 1], bz = T[3 * k + 2];
            float na = fmaf(ax, ax, fmaf(ay, ay, az * az));
            float nb = fmaf(bx, bx, fmaf(by, by, bz * bz));
            float dot = fmaf(ax, bx, fmaf(ay, by, az * bz));
            float r = __frsqrt_rn(fmaxf(na, 1e-24f)) * __frsqrt_rn(fmaxf(nb, 1e-24f));
            sn += wk * (1.0f - dot * r);
        }
    }

    // ---- block reduction -> per-block partial slots
    float vals[6] = {s3d, s2, sv, sd, sn, sc};
    const int wid = tid >> 6, lane = tid & 63;
#pragma unroll
    for (int k = 0; k < 6; k++) {
        float r = wredf(vals[k]);
        if (lane == 0) sred[wid][k] = r;
    }
    __syncthreads();
    if (tid < 6) {
        float tt = sred[0][tid] + sred[1][tid] + sred[2][tid] + sred[3][tid];
        atomicAdd(&ws[PART_F + tid * NBLK + (int)blockIdx.x], tt);
    }
    grid.sync();
    __threadfence();

    // ---- final combine: block 0
    if (blockIdx.x == 0) {
        double loc[6] = {0, 0, 0, 0, 0, 0};
        for (int j = tid; j < NBLK; j += THR) {
#pragma unroll
            for (int k = 0; k < 6; k++) loc[k] += (double)ws[PART_F + k * NBLK + j];
        }
        __shared__ double dred[4][6];
#pragma unroll
        for (int k = 0; k < 6; k++) {
            double v = loc[k];
#pragma unroll
            for (int o = 32; o > 0; o >>= 1) v += __shfl_down(v, o, 64);
            if (lane == 0) dred[wid][k] = v;
        }
        __syncthreads();
        if (tid == 0) {
            double a[6];
#pragma unroll
            for (int k = 0; k < 6; k++)
                a[k] = dred[0][k] + dred[1][k] + dred[2][k] + dred[3][k];
            double nv = (double)sNv;
            double d1 = nv + 1e-6;
            double d3 = 3.0 * nv + 1e-6;
            out[0] = (float)(a[0] / d3 + 0.1 * (a[1] / (2.0 * nv + 1e-6) + a[2] / d1 + a[3] / d3)
                             + 0.5 * (a[4] / d1) + 0.2 * (a[5] / d1));
        }
    }
}

// =================== FALLBACK (round-7, proven) ===================
__global__ __launch_bounds__(256) void k_group(const float* __restrict__ pp,
                                               const float* __restrict__ tp,
                                               const int* __restrict__ mask,
                                               const int* __restrict__ grp,
                                               float* __restrict__ ws) {
    __shared__ float4 bufA[768], bufB[768];
    __shared__ float sP[GG], sT[GG], sC[GG];
    const int tid = threadIdx.x;
    if (tid < GG) { sP[tid] = 0.f; sT[tid] = 0.f; sC[tid] = 0.f; }

    const int base = blockIdx.x * FB_PTS;
    const int b = base >> 18;
    const int p0 = base + 4 * tid;

    const float4* gx = (const float4*)(pp + (size_t)base * 3);
    const float4* gy = (const float4*)(tp + (size_t)base * 3);
#pragma unroll
    for (int j = 0; j < 3; j++) {
        bufA[tid + 256 * j] = gx[tid + 256 * j];
        bufB[tid + 256 * j] = gy[tid + 256 * j];
    }
    const int4 M  = *(const int4*)(mask + p0);
    const int4 Gp = *(const int4*)(grp + p0);
    __syncthreads();

    float4 a0 = bufA[3 * tid], a1 = bufA[3 * tid + 1], a2 = bufA[3 * tid + 2];
    float4 b0 = bufB[3 * tid], b1 = bufB[3 * tid + 1], b2 = bufB[3 * tid + 2];
    if (M.x) { atomicAdd(&sP[Gp.x], a0.z); atomicAdd(&sT[Gp.x], b0.z); atomicAdd(&sC[Gp.x], 1.f); }
    if (M.y) { atomicAdd(&sP[Gp.y], a1.y); atomicAdd(&sT[Gp.y], b1.y); atomicAdd(&sC[Gp.y], 1.f); }
    if (M.z) { atomicAdd(&sP[Gp.z], a2.x); atomicAdd(&sT[Gp.z], b2.x); atomicAdd(&sC[Gp.z], 1.f); }
    if (M.w) { atomicAdd(&sP[Gp.w], a2.w); atomicAdd(&sT[Gp.w], b2.w); atomicAdd(&sC[Gp.w], 1.f); }
    __syncthreads();

    if (tid < GG) {
        float c = sC[tid];
        if (c != 0.0f) {
            int e = b * GG + tid;
            atomicAdd(&ws[ZP_F + e], sP[tid]);
            atomicAdd(&ws[ZT_F + e], sT[tid]);
            atomicAdd(&ws[CNT_F + e], c);
        }
    }
}

__global__ __launch_bounds__(512) void k_groups_final(float* __restrict__ ws) {
    __shared__ float red[512];
    int j = threadIdx.x;
    float c  = ws[CNT_F + j];
    float mP = (c > 0.f) ? (ws[ZP_F + j] / fmaxf(c, 1.f)) : 1.0f;
    float mT = (c > 0.f) ? (ws[ZT_F + j] / fmaxf(c, 1.f)) : 1.0f;
    ws[FB_PAIR + 2 * j]     = 1.0f / fmaxf(fabsf(mP), 1e-6f);
    ws[FB_PAIR + 2 * j + 1] = 1.0f / fmaxf(fabsf(mT), 1e-6f);
    red[j] = c;
    __syncthreads();
    for (int s = 256; s > 0; s >>= 1) {
        if (j < s) red[j] += red[j + s];
        __syncthreads();
    }
    if (j == 0) ws[FB_NV] = red[0];
}

__global__ __launch_bounds__(256) void k_loss(const float* __restrict__ pp,
                                              const float* __restrict__ tp,
                                              const float* __restrict__ p2,
                                              const float* __restrict__ t2,
                                              const float* __restrict__ pv,
                                              const float* __restrict__ tv,
                                              const float* __restrict__ pd,
                                              const float* __restrict__ td,
                                              const float* __restrict__ pn,
                                              const float* __restrict__ tn,
                                              const float* __restrict__ cf,
                                              const int* __restrict__ mask,
                                              const int* __restrict__ grp,
                                              float* __restrict__ ws) {
    __shared__ float4 bufA[768], bufB[768];
    const int tid = threadIdx.x;
    const int base = blockIdx.x * FB_PTS;
    const int p0 = base + 4 * tid;
    const int bb6 = (base >> 18) << 6;
    const float* pairs = ws + FB_PAIR;

    const int4 M  = *(const int4*)(mask + p0);
    const int4 Gp = *(const int4*)(grp + p0);
    const float w[4] = {(float)M.x, (float)M.y, (float)M.z, (float)M.w};
    const int Gs[4] = {Gp.x, Gp.y, Gp.z, Gp.w};
    float iP[4], iT[4];
#pragma unroll
    for (int k = 0; k < 4; k++) {
        float2 pr = *(const float2*)(pairs + 2 * (bb6 | Gs[k]));
        iP[k] = pr.x; iT[k] = pr.y;
    }

    float s3d = 0.f, s2 = 0.f, sv = 0.f, sd = 0.f, sn = 0.f, sc = 0.f;

    {
        float4 Aa = ((const float4*)(p2 + 2 * (size_t)p0))[0];
        float4 Ab = ((const float4*)(p2 + 2 * (size_t)p0))[1];
        float4 Ba = ((const float4*)(t2 + 2 * (size_t)p0))[0];
        float4 Bb = ((const float4*)(t2 + 2 * (size_t)p0))[1];
        s2 = w[0] * (fabsf(Aa.x - Ba.x) + fabsf(Aa.y - Ba.y))
           + w[1] * (fabsf(Aa.z - Ba.z) + fabsf(Aa.w - Ba.w))
           + w[2] * (fabsf(Ab.x - Bb.x) + fabsf(Ab.y - Bb.y))
           + w[3] * (fabsf(Ab.z - Bb.z) + fabsf(Ab.w - Bb.w));
    }
    {
        float4 X  = *(const float4*)(pv + p0);
        float4 Tg = *(const float4*)(tv + p0);
        float4 C  = *(const float4*)(cf + p0);
        const float xs[4] = {X.x, X.y, X.z, X.w};
        const float ts[4] = {Tg.x, Tg.y, Tg.z, Tg.w};
        const float cs[4] = {C.x, C.y, C.z, C.w};
#pragma unroll
        for (int k = 0; k < 4; k++) {
            float x = xs[k];
            float soft = flog2(1.0f + fexp2(-fabsf(x) * LOG2E)) * LN2;
            sv += w[k] * (fmaxf(x, 0.f) - x * ts[k] + soft);
            sc += w[k] * cs[k];
        }
    }
    {
        const float4* gx = (const float4*)(pp + (size_t)base * 3);
        const float4* gy = (const float4*)(tp + (size_t)base * 3);
#pragma unroll
        for (int j = 0; j < 3; j++) {
            bufA[tid + 256 * j] = gx[tid + 256 * j];
            bufB[tid + 256 * j] = gy[tid + 256 * j];
        }
        __syncthreads();
        float P[12], T[12];
        *(float4*)&P[0] = bufA[3 * tid]; *(float4*)&P[4] = bufA[3 * tid + 1]; *(float4*)&P[8] = bufA[3 * tid + 2];
        *(float4*)&T[0] = bufB[3 * tid]; *(float4*)&T[4] = bufB[3 * tid + 1]; *(float4*)&T[8] = bufB[3 * tid + 2];
        __syncthreads();
#pragma unroll
        for (int k = 0; k < 4; k++) {
            float acc = 0.f;
#pragma unroll
            for (int c = 0; c < 3; c++) {
                float a = P[3 * k + c] * iP[k];
                float b = T[3 * k + c] * iT[k];
                acc += fabsf(copysignf(flog1p(fabsf(a)), a) - copysignf(flog1p(fabsf(b)), b));
            }
            s3d += w[k] * acc;
        }
    }
    {
        const float4* gx = (const float4*)(pd + (size_t)base * 3);
        const float4* gy = (const float4*)(td + (size_t)base * 3);
#pragma unroll
        for (int j = 0; j < 3; j++) {
            bufA[tid + 256 * j] = gx[tid + 256 * j];
            bufB[tid + 256 * j] = gy[tid + 256 * j];
        }
        __syncthreads();
        float P[12], T[12];
        *(float4*)&P[0] = bufA[3 * tid]; *(float4*)&P[4] = bufA[3 * tid + 1]; *(float4*)&P[8] = bufA[3 * tid + 2];
        *(float4*)&T[0] = bufB[3 * tid]; *(float4*)&T[4] = bufB[3 * tid + 1]; *(float4*)&T[8] = bufB[3 * tid + 2];
        __syncthreads();
#pragma unroll
        for (int k = 0; k < 4; k++) {
            sd += w[k] * (fabsf(P[3 * k] - T[3 * k]) + fabsf(P[3 * k + 1] - T[3 * k + 1])
                        + fabsf(P[3 * k + 2] - T[3 * k + 2]));
        }
    }
    {
        const float4* gx = (const float4*)(pn + (size_t)base * 3);
        const float4* gy = (const float4*)(tn + (size_t)base * 3);
#pragma unroll
        for (int j = 0; j < 3; j++) {
            bufA[tid + 256 * j] = gx[tid + 256 * j];
            bufB[tid + 256 * j] = gy[tid + 256 * j];
        }
        __syncthreads();
        float P[12], T[12];
        *(float4*)&P[0] = bufA[3 * tid]; *(float4*)&P[4] = bufA[3 * tid + 1]; *(float4*)&P[8] = bufA[3 * tid + 2];
        *(float4*)&T[0] = bufB[3 * tid]; *(float4*)&T[4] = bufB[3 * tid + 1]; *(float4*)&T[8] = bufB[3 * tid + 2];
#pragma unroll
        for (int k = 0; k < 4; k++) {
            float ax = P[3 * k], ay = P[3 * k + 1], az = P[3 * k + 2];
            float bx = T[3 * k], by = T[3 * k + 1], bz = T[3 * k + 2];
            float na = fmaf(ax, ax, fmaf(ay, ay, az * az));
            float nb = fmaf(bx, bx, fmaf(by, by, bz * bz));
            float dot = fmaf(ax, bx, fmaf(ay, by, az * bz));
            float r = __frsqrt_rn(fmaxf(na, 1e-24f)) * __frsqrt_rn(fmaxf(nb, 1e-24f));
            sn += w[k] * (1.0f - dot * r);
        }
    }

    __shared__ float sred[4][6];
    float vals[6] = {s3d, s2, sv, sd, sn, sc};
    int wid = threadIdx.x >> 6, lane = threadIdx.x & 63;
#pragma unroll
    for (int k = 0; k < 6; k++) {
        float r = wredf(vals[k]);
        if (lane == 0) sred[wid][k] = r;
    }
    __syncthreads();
    if (threadIdx.x < 6) {
        float tt = sred[0][threadIdx.x] + sred[1][threadIdx.x]
                 + sred[2][threadIdx.x] + sred[3][threadIdx.x];
        ws[FB_PART + threadIdx.x * FB_NBLK + blockIdx.x] = tt;
    }
}

__global__ __launch_bounds__(256) void k_final(const float* __restrict__ ws,
                                               float* __restrict__ out) {
    const float* part = ws + FB_PART;
    double loc[6] = {0, 0, 0, 0, 0, 0};
    for (int j = threadIdx.x; j < FB_NBLK; j += 256) {
#pragma unroll
        for (int k = 0; k < 6; k++) loc[k] += (double)part[k * FB_NBLK + j];
    }
    __shared__ double dred[4][6];
    int wid = threadIdx.x >> 6, lane = threadIdx.x & 63;
#pragma unroll
    for (int k = 0; k < 6; k++) {
        double v = loc[k];
#pragma unroll
        for (int o = 32; o > 0; o >>= 1) v += __shfl_down(v, o, 64);
        if (lane == 0) dred[wid][k] = v;
    }
    __syncthreads();
    if (threadIdx.x == 0) {
        double a[6];
#pragma unroll
        for (int k = 0; k < 6; k++)
            a[k] = dred[0][k] + dred[1][k] + dred[2][k] + dred[3][k];
        double nv = (double)ws[FB_NV];
        double d1 = nv + 1e-6;
        double d3 = 3.0 * nv + 1e-6;
        out[0] = (float)(a[0] / d3 + 0.1 * (a[1] / (2.0 * nv + 1e-6) + a[2] / d1 + a[3] / d3)
                         + 0.5 * (a[4] / d1) + 0.2 * (a[5] / d1));
    }
}

extern "C" void kernel_launch(void* const* d_in, const int* in_sizes, int n_in,
                              void* d_out, int out_size, void* d_ws, size_t ws_size,
                              hipStream_t stream) {
    const float* pp = (const float*)d_in[0];
    const float* tp = (const float*)d_in[1];
    const float* p2 = (const float*)d_in[2];
    const float* t2 = (const float*)d_in[3];
    const float* pv = (const float*)d_in[4];
    const float* tv = (const float*)d_in[5];
    const float* pd = (const float*)d_in[6];
    const float* td = (const float*)d_in[7];
    const float* pn = (const float*)d_in[8];
    const float* tn = (const float*)d_in[9];
    const float* cf = (const float*)d_in[10];
    const int* mask = (const int*)d_in[11];
    const int* grp  = (const int*)d_in[12];
    float* ws = (float*)d_ws;
    float* out = (float*)d_out;

    (void)hipMemsetAsync(d_ws, 0, WS_ZERO_BYTES, stream);

    void* args[] = {
        (void*)&pp, (void*)&tp, (void*)&p2, (void*)&t2, (void*)&pv, (void*)&tv,
        (void*)&pd, (void*)&td, (void*)&pn, (void*)&tn, (void*)&cf,
        (void*)&mask, (void*)&grp, (void*)&ws, (void*)&out
    };
    hipError_t e = hipLaunchCooperativeKernel((const void*)k_fused, dim3(NBLK), dim3(THR),
                                              args, 0, stream);
    if (e != hipSuccess) {
        // fallback: proven 4-kernel path
        k_group<<<FB_NBLK, 256, 0, stream>>>(pp, tp, mask, grp, ws);
        k_groups_final<<<1, 512, 0, stream>>>(ws);
        k_loss<<<FB_NBLK, 256, 0, stream>>>(pp, tp, p2, t2, pv, tv, pd, td, pn, tn, cf, mask, grp, ws);
        k_final<<<1, 256, 0, stream>>>(ws, out);
    }
}

// Round 11
// 78.947 us; speedup vs baseline: 5.0446x; 5.0446x over previous
//
#include <hip/hip_runtime.h>
#include <math.h>

#define GG   64
#define NBG  512           // B*G
#define TOT  2097152       // B*N
#define PTS  1024          // points per block (256 thr x 4)
#define NBLK (TOT / PTS)   // 2048

// ws float layout:
//   [0    ..  512) zsumP
//   [512  .. 1024) zsumT
//   [1024 .. 1536) cnt
//   [1536 .. 2560) interleaved (invP,invT) pairs
//   [2560]         nvalid
//   [2816 .. 2816+6*2048) per-block partials, transposed
#define ZP_F   0
#define ZT_F   512
#define CNT_F  1024
#define PAIR_F 1536
#define NV_F   2560
#define PART_F 2816
#define WS_ZERO_BYTES (1536 * 4)

#define LN2   0.6931471805599453f
#define LOG2E 1.4426950408889634f

typedef float vf4 __attribute__((ext_vector_type(4)));
typedef int   vi4 __attribute__((ext_vector_type(4)));

__device__ __forceinline__ float fexp2(float x) { return __builtin_amdgcn_exp2f(x); }
__device__ __forceinline__ float flog2(float x) { return __builtin_amdgcn_logf(x); }
__device__ __forceinline__ float flog1p(float x) { return flog2(1.0f + x) * LN2; }

// non-temporal vector loads via native clang vector types
__device__ __forceinline__ float4 ntl4(const float4* p) {
    vf4 v = __builtin_nontemporal_load((const vf4*)p);
    return make_float4(v.x, v.y, v.z, v.w);
}
__device__ __forceinline__ int4 ntl4i(const int4* p) {
    vi4 v = __builtin_nontemporal_load((const vi4*)p);
    return make_int4(v.x, v.y, v.z, v.w);
}

__device__ __forceinline__ float wredf(float v) {
#pragma unroll
    for (int o = 32; o > 0; o >>= 1) v += __shfl_down(v, o, 64);
    return v;
}

// ---- Kernel 1: per-(b,g) z sums + counts. LDS-staged coalesced nt reads.
__global__ __launch_bounds__(256) void k_group(const float* __restrict__ pp,
                                               const float* __restrict__ tp,
                                               const int* __restrict__ mask,
                                               const int* __restrict__ grp,
                                               float* __restrict__ ws) {
    __shared__ float4 bufA[768], bufB[768];
    __shared__ float sP[GG], sT[GG], sC[GG];
    const int tid = threadIdx.x;
    if (tid < GG) { sP[tid] = 0.f; sT[tid] = 0.f; sC[tid] = 0.f; }

    const int base = blockIdx.x * PTS;
    const int b = base >> 18;
    const int p0 = base + 4 * tid;

    const float4* gx = (const float4*)(pp + (size_t)base * 3);
    const float4* gy = (const float4*)(tp + (size_t)base * 3);
#pragma unroll
    for (int j = 0; j < 3; j++) {
        bufA[tid + 256 * j] = ntl4(&gx[tid + 256 * j]);
        bufB[tid + 256 * j] = ntl4(&gy[tid + 256 * j]);
    }
    const int4 M  = ntl4i((const int4*)(mask + p0));
    const int4 Gp = ntl4i((const int4*)(grp + p0));
    __syncthreads();

    float4 a0 = bufA[3 * tid], a1 = bufA[3 * tid + 1], a2 = bufA[3 * tid + 2];
    float4 b0 = bufB[3 * tid], b1 = bufB[3 * tid + 1], b2 = bufB[3 * tid + 2];
    // z components: pt0=a0.z pt1=a1.y pt2=a2.x pt3=a2.w
    if (M.x) { atomicAdd(&sP[Gp.x], a0.z); atomicAdd(&sT[Gp.x], b0.z); atomicAdd(&sC[Gp.x], 1.f); }
    if (M.y) { atomicAdd(&sP[Gp.y], a1.y); atomicAdd(&sT[Gp.y], b1.y); atomicAdd(&sC[Gp.y], 1.f); }
    if (M.z) { atomicAdd(&sP[Gp.z], a2.x); atomicAdd(&sT[Gp.z], b2.x); atomicAdd(&sC[Gp.z], 1.f); }
    if (M.w) { atomicAdd(&sP[Gp.w], a2.w); atomicAdd(&sT[Gp.w], b2.w); atomicAdd(&sC[Gp.w], 1.f); }
    __syncthreads();

    if (tid < GG) {
        float c = sC[tid];
        if (c != 0.0f) {
            int e = b * GG + tid;
            atomicAdd(&ws[ZP_F + e], sP[tid]);
            atomicAdd(&ws[ZT_F + e], sT[tid]);
            atomicAdd(&ws[CNT_F + e], c);
        }
    }
}

// ---- Kernel 2: finalize interleaved inverse safe means + nvalid. 1 block x 512
__global__ __launch_bounds__(512) void k_groups_final(float* __restrict__ ws) {
    __shared__ float red[NBG];
    int j = threadIdx.x;
    float c  = ws[CNT_F + j];
    float mP = (c > 0.f) ? (ws[ZP_F + j] / fmaxf(c, 1.f)) : 1.0f;
    float mT = (c > 0.f) ? (ws[ZT_F + j] / fmaxf(c, 1.f)) : 1.0f;
    ws[PAIR_F + 2 * j]     = 1.0f / fmaxf(fabsf(mP), 1e-6f);
    ws[PAIR_F + 2 * j + 1] = 1.0f / fmaxf(fabsf(mT), 1e-6f);
    red[j] = c;
    __syncthreads();
    for (int s = 256; s > 0; s >>= 1) {
        if (j < s) red[j] += red[j + s];
        __syncthreads();
    }
    if (j == 0) ws[NV_F] = red[0];
}

// ---- Kernel 3: main loss. 2048 blocks x 256 thr x 4 pts. xyz via LDS; all nt loads.
__global__ __launch_bounds__(256) void k_loss(const float* __restrict__ pp,
                                              const float* __restrict__ tp,
                                              const float* __restrict__ p2,
                                              const float* __restrict__ t2,
                                              const float* __restrict__ pv,
                                              const float* __restrict__ tv,
                                              const float* __restrict__ pd,
                                              const float* __restrict__ td,
                                              const float* __restrict__ pn,
                                              const float* __restrict__ tn,
                                              const float* __restrict__ cf,
                                              const int* __restrict__ mask,
                                              const int* __restrict__ grp,
                                              float* __restrict__ ws) {
    __shared__ float4 bufA[768], bufB[768];
    const int tid = threadIdx.x;
    const int base = blockIdx.x * PTS;
    const int p0 = base + 4 * tid;
    const int bb6 = (base >> 18) << 6;
    const float* pairs = ws + PAIR_F;

    // ---- direct (single-touch, coalesced) nt loads + their terms first
    const int4 M  = ntl4i((const int4*)(mask + p0));
    const int4 Gp = ntl4i((const int4*)(grp + p0));
    const float w[4] = {(float)M.x, (float)M.y, (float)M.z, (float)M.w};
    const int Gs[4] = {Gp.x, Gp.y, Gp.z, Gp.w};
    float iP[4], iT[4];
#pragma unroll
    for (int k = 0; k < 4; k++) {
        float2 pr = *(const float2*)(pairs + 2 * (bb6 | Gs[k]));   // cached (hot table)
        iP[k] = pr.x; iT[k] = pr.y;
    }

    float s3d = 0.f, s2 = 0.f, sv = 0.f, sd = 0.f, sn = 0.f, sc = 0.f;

    {   // L_2D
        float4 Aa = ntl4(((const float4*)(p2 + 2 * (size_t)p0)) + 0);
        float4 Ab = ntl4(((const float4*)(p2 + 2 * (size_t)p0)) + 1);
        float4 Ba = ntl4(((const float4*)(t2 + 2 * (size_t)p0)) + 0);
        float4 Bb = ntl4(((const float4*)(t2 + 2 * (size_t)p0)) + 1);
        s2 = w[0] * (fabsf(Aa.x - Ba.x) + fabsf(Aa.y - Ba.y))
           + w[1] * (fabsf(Aa.z - Ba.z) + fabsf(Aa.w - Ba.w))
           + w[2] * (fabsf(Ab.x - Bb.x) + fabsf(Ab.y - Bb.y))
           + w[3] * (fabsf(Ab.z - Bb.z) + fabsf(Ab.w - Bb.w));
    }
    {   // L_vis + L_conf
        float4 X  = ntl4((const float4*)(pv + p0));
        float4 Tg = ntl4((const float4*)(tv + p0));
        float4 C  = ntl4((const float4*)(cf + p0));
        const float xs[4] = {X.x, X.y, X.z, X.w};
        const float ts[4] = {Tg.x, Tg.y, Tg.z, Tg.w};
        const float cs[4] = {C.x, C.y, C.z, C.w};
#pragma unroll
        for (int k = 0; k < 4; k++) {
            float x = xs[k];
            float soft = flog2(1.0f + fexp2(-fabsf(x) * LOG2E)) * LN2;
            sv += w[k] * (fmaxf(x, 0.f) - x * ts[k] + soft);
            sc += w[k] * cs[k];
        }
    }

    // ---- Phase 1: pp/tp -> L_3D
    {
        const float4* gx = (const float4*)(pp + (size_t)base * 3);
        const float4* gy = (const float4*)(tp + (size_t)base * 3);
#pragma unroll
        for (int j = 0; j < 3; j++) {
            bufA[tid + 256 * j] = ntl4(&gx[tid + 256 * j]);
            bufB[tid + 256 * j] = ntl4(&gy[tid + 256 * j]);
        }
        __syncthreads();
        float P[12], T[12];
        *(float4*)&P[0] = bufA[3 * tid]; *(float4*)&P[4] = bufA[3 * tid + 1]; *(float4*)&P[8] = bufA[3 * tid + 2];
        *(float4*)&T[0] = bufB[3 * tid]; *(float4*)&T[4] = bufB[3 * tid + 1]; *(float4*)&T[8] = bufB[3 * tid + 2];
        __syncthreads();
#pragma unroll
        for (int k = 0; k < 4; k++) {
            float acc = 0.f;
#pragma unroll
            for (int c = 0; c < 3; c++) {
                float a = P[3 * k + c] * iP[k];
                float b = T[3 * k + c] * iT[k];
                acc += fabsf(copysignf(flog1p(fabsf(a)), a) - copysignf(flog1p(fabsf(b)), b));
            }
            s3d += w[k] * acc;
        }
    }
    // ---- Phase 2: pd/td -> L_disp
    {
        const float4* gx = (const float4*)(pd + (size_t)base * 3);
        const float4* gy = (const float4*)(td + (size_t)base * 3);
#pragma unroll
        for (int j = 0; j < 3; j++) {
            bufA[tid + 256 * j] = ntl4(&gx[tid + 256 * j]);
            bufB[tid + 256 * j] = ntl4(&gy[tid + 256 * j]);
        }
        __syncthreads();
        float P[12], T[12];
        *(float4*)&P[0] = bufA[3 * tid]; *(float4*)&P[4] = bufA[3 * tid + 1]; *(float4*)&P[8] = bufA[3 * tid + 2];
        *(float4*)&T[0] = bufB[3 * tid]; *(float4*)&T[4] = bufB[3 * tid + 1]; *(float4*)&T[8] = bufB[3 * tid + 2];
        __syncthreads();
#pragma unroll
        for (int k = 0; k < 4; k++) {
            float acc = fabsf(P[3 * k] - T[3 * k]) + fabsf(P[3 * k + 1] - T[3 * k + 1])
                      + fabsf(P[3 * k + 2] - T[3 * k + 2]);
            sd += w[k] * acc;
        }
    }
    // ---- Phase 3: pn/tn -> L_normal
    {
        const float4* gx = (const float4*)(pn + (size_t)base * 3);
        const float4* gy = (const float4*)(tn + (size_t)base * 3);
#pragma unroll
        for (int j = 0; j < 3; j++) {
            bufA[tid + 256 * j] = ntl4(&gx[tid + 256 * j]);
            bufB[tid + 256 * j] = ntl4(&gy[tid + 256 * j]);
        }
        __syncthreads();
        float P[12], T[12];
        *(float4*)&P[0] = bufA[3 * tid]; *(float4*)&P[4] = bufA[3 * tid + 1]; *(float4*)&P[8] = bufA[3 * tid + 2];
        *(float4*)&T[0] = bufB[3 * tid]; *(float4*)&T[4] = bufB[3 * tid + 1]; *(float4*)&T[8] = bufB[3 * tid + 2];
#pragma unroll
        for (int k = 0; k < 4; k++) {
            float ax = P[3 * k], ay = P[3 * k + 1], az = P[3 * k + 2];
            float bx = T[3 * k], by = T[3 * k + 1], bz = T[3 * k + 2];
            float na = fmaf(ax, ax, fmaf(ay, ay, az * az));
            float nb = fmaf(bx, bx, fmaf(by, by, bz * bz));
            float dot = fmaf(ax, bx, fmaf(ay, by, az * bz));
            float r = __frsqrt_rn(fmaxf(na, 1e-24f)) * __frsqrt_rn(fmaxf(nb, 1e-24f));
            sn += w[k] * (1.0f - dot * r);
        }
    }

    // block reduction -> one non-atomic write per (block, term)
    __shared__ float sred[4][6];
    float vals[6] = {s3d, s2, sv, sd, sn, sc};
    int wid = threadIdx.x >> 6, lane = threadIdx.x & 63;
#pragma unroll
    for (int k = 0; k < 6; k++) {
        float r = wredf(vals[k]);
        if (lane == 0) sred[wid][k] = r;
    }
    __syncthreads();
    if (threadIdx.x < 6) {
        float tt = sred[0][threadIdx.x] + sred[1][threadIdx.x]
                 + sred[2][threadIdx.x] + sred[3][threadIdx.x];
        ws[PART_F + threadIdx.x * NBLK + blockIdx.x] = tt;
    }
}

// ---- Kernel 4: final reduce (2048 partials x 6) + combine. 1 block x 256 thr
__global__ __launch_bounds__(256) void k_final(const float* __restrict__ ws,
                                               float* __restrict__ out) {
    const float* part = ws + PART_F;
    double loc[6] = {0, 0, 0, 0, 0, 0};
    for (int j = threadIdx.x; j < NBLK; j += 256) {
#pragma unroll
        for (int k = 0; k < 6; k++) loc[k] += (double)part[k * NBLK + j];
    }
    __shared__ double dred[4][6];
    int wid = threadIdx.x >> 6, lane = threadIdx.x & 63;
#pragma unroll
    for (int k = 0; k < 6; k++) {
        double v = loc[k];
#pragma unroll
        for (int o = 32; o > 0; o >>= 1) v += __shfl_down(v, o, 64);
        if (lane == 0) dred[wid][k] = v;
    }
    __syncthreads();
    if (threadIdx.x == 0) {
        double a[6];
#pragma unroll
        for (int k = 0; k < 6; k++)
            a[k] = dred[0][k] + dred[1][k] + dred[2][k] + dred[3][k];
        double nv = (double)ws[NV_F];
        double d1 = nv + 1e-6;
        double d3 = 3.0 * nv + 1e-6;
        double l3d   = a[0] / d3;
        double l2d   = a[1] / (2.0 * nv + 1e-6);
        double lvis  = a[2] / d1;
        double ldisp = a[3] / d3;   // disp is (B,N,3): mask broadcasts to 3 channels
        double lnorm = a[4] / d1;
        double lconf = a[5] / d1;
        out[0] = (float)(l3d + 0.1 * (l2d + lvis + ldisp) + 0.5 * lnorm + 0.2 * lconf);
    }
}

extern "C" void kernel_launch(void* const* d_in, const int* in_sizes, int n_in,
                              void* d_out, int out_size, void* d_ws, size_t ws_size,
                              hipStream_t stream) {
    const float* pp = (const float*)d_in[0];
    const float* tp = (const float*)d_in[1];
    const float* p2 = (const float*)d_in[2];
    const float* t2 = (const float*)d_in[3];
    const float* pv = (const float*)d_in[4];
    const float* tv = (const float*)d_in[5];
    const float* pd = (const float*)d_in[6];
    const float* td = (const float*)d_in[7];
    const float* pn = (const float*)d_in[8];
    const float* tn = (const float*)d_in[9];
    const float* cf = (const float*)d_in[10];
    const int* mask = (const int*)d_in[11];
    const int* grp  = (const int*)d_in[12];
    float* ws = (float*)d_ws;
    float* out = (float*)d_out;

    (void)hipMemsetAsync(d_ws, 0, WS_ZERO_BYTES, stream);
    k_group<<<NBLK, 256, 0, stream>>>(pp, tp, mask, grp, ws);
    k_groups_final<<<1, NBG, 0, stream>>>(ws);
    k_loss<<<NBLK, 256, 0, stream>>>(pp, tp, p2, t2, pv, tv, pd, td, pn, tn, cf, mask, grp, ws);
    k_final<<<1, 256, 0, stream>>>(ws, out);
}